// Round 6
// baseline (401.750 us; speedup 1.0000x reference)
//
#include <hip/hip_runtime.h>
#include <hip/hip_bf16.h>
#include <stdint.h>

typedef __bf16 bf16_t;
typedef __bf16 bf16x4 __attribute__((ext_vector_type(4)));
typedef __bf16 bf16x8 __attribute__((ext_vector_type(8)));
typedef float floatx4 __attribute__((ext_vector_type(4)));

#define B_ 32
#define HP 58
#define WP 66

// ws layout (bytes)
#define XPAD_OFF   0u
#define WAGG_OFF   62717952u     // 32*58*66*256*2
#define POOLED_OFF 100466688u    // + 32*9*256*256*2
#define ATTN_OFF   100499456u
#define BIASAGG_OFF 100499968u

__device__ __forceinline__ void async_copy16(const void* gsrc, void* ldst) {
  __builtin_amdgcn_global_load_lds(
      (const __attribute__((address_space(1))) unsigned int*)gsrc,
      (__attribute__((address_space(3))) unsigned int*)ldst, 16, 0, 0);
}

// ---------------- kernel 1: pad + convert + GAP partial sums ----------------
__global__ __launch_bounds__(256)
void pad_pool(const float* __restrict__ x, bf16_t* __restrict__ xpad,
              float* __restrict__ pooled) {
  const int hp = blockIdx.x;   // 0..57
  const int b  = blockIdx.y;
  const int t  = threadIdx.x;
  const int c4 = (t & 63) << 2;   // 0..252 (float4 channel group)
  const int wq = t >> 6;          // 0..3
  const int h  = hp - 1;
  const bool hvalid = (h >= 0) && (h < 56);
  bf16_t* dst = xpad + ((size_t)(b * 58 + hp)) * (66 * 256);
  const float* srcrow = x + ((size_t)(b * 56 + (hvalid ? h : 0))) * (56 * 256);
  floatx4 sum = {0.f, 0.f, 0.f, 0.f};
  for (int wp = wq; wp < 66; wp += 4) {
    const int w = wp - 1;
    floatx4 v = {0.f, 0.f, 0.f, 0.f};
    if (hvalid && (unsigned)w < 56u) {
      v = *(const floatx4*)(srcrow + w * 256 + c4);
      sum += v;
    }
    bf16x4 r;
#pragma unroll
    for (int j = 0; j < 4; ++j) r[j] = (bf16_t)v[j];
    *(bf16x4*)(dst + wp * 256 + c4) = r;
  }
  __shared__ floatx4 red[4][64];
  red[wq][t & 63] = sum;
  __syncthreads();
  if (hvalid && t < 64) {
    floatx4 s = red[0][t] + red[1][t] + red[2][t] + red[3][t];
#pragma unroll
    for (int j = 0; j < 4; ++j) atomicAdd(&pooled[b * 256 + t * 4 + j], s[j]);
  }
}

// ---------------- kernel 2: router MLP + softmax + bias agg ----------------
__global__ __launch_bounds__(256)
void router(const float* __restrict__ pooled, const float* __restrict__ w1,
            const float* __restrict__ b1, const float* __restrict__ w2,
            const float* __restrict__ b2, const float* __restrict__ biases,
            float* __restrict__ attn, float* __restrict__ biasagg) {
  __shared__ float ps[8192];
  __shared__ float w1s[16384];
  __shared__ float hs[2048];
  __shared__ float lg[128];
  __shared__ float at[128];
  const int t = threadIdx.x;
  for (int i = t; i < 8192; i += 256) ps[i] = pooled[i] * (1.0f / 3136.0f);
  for (int i = t; i < 4096; i += 256)
    *(floatx4*)&w1s[i * 4] = *(const floatx4*)&w1[i * 4];
  __syncthreads();
  for (int task = t; task < 2048; task += 256) {
    const int b = task >> 6, j = task & 63;
    const float* pb = ps + b * 256;
    float s0 = 0.f, s1 = 0.f, s2 = 0.f, s3 = 0.f;
#pragma unroll 4
    for (int c = 0; c < 256; c += 4) {
      s0 += pb[c]     * w1s[c * 64 + j];
      s1 += pb[c + 1] * w1s[(c + 1) * 64 + j];
      s2 += pb[c + 2] * w1s[(c + 2) * 64 + j];
      s3 += pb[c + 3] * w1s[(c + 3) * 64 + j];
    }
    hs[task] = fmaxf((s0 + s1) + (s2 + s3) + b1[j], 0.f);
  }
  __syncthreads();
  if (t < 128) {
    int b = t >> 2, k = t & 3;
    float s = b2[k];
    const float* hb = hs + b * 64;
#pragma unroll 4
    for (int j = 0; j < 64; ++j) s += hb[j] * w2[j * 4 + k];
    lg[t] = s * (1.0f / 30.0f);
  }
  __syncthreads();
  if (t < 32) {
    int b = t;
    float z0 = lg[b*4], z1 = lg[b*4+1], z2 = lg[b*4+2], z3 = lg[b*4+3];
    float m = fmaxf(fmaxf(z0, z1), fmaxf(z2, z3));
    float e0 = expf(z0-m), e1 = expf(z1-m), e2 = expf(z2-m), e3 = expf(z3-m);
    float inv = 1.0f / (e0 + e1 + e2 + e3);
    at[b*4] = e0*inv; at[b*4+1] = e1*inv; at[b*4+2] = e2*inv; at[b*4+3] = e3*inv;
    attn[b*4] = at[b*4]; attn[b*4+1] = at[b*4+1];
    attn[b*4+2] = at[b*4+2]; attn[b*4+3] = at[b*4+3];
  }
  __syncthreads();
  for (int i = t; i < 8192; i += 256) {
    int b = i >> 8, f = i & 255;
    biasagg[i] = at[b*4]*biases[f] + at[b*4+1]*biases[256+f]
               + at[b*4+2]*biases[512+f] + at[b*4+3]*biases[768+f];
  }
}

// ---------------- kernel 3: weight aggregation + transpose to [b][tap][f][c] ----------------
__global__ __launch_bounds__(256)
void wagg_kernel(const float* __restrict__ kers, const float* __restrict__ attn,
                 bf16_t* __restrict__ wagg) {
  const int lid = blockIdx.x;     // 0..575
  const int xcd = lid & 7;
  const int sl  = lid >> 3;       // 0..71
  const int c8  = sl & 7;         // 32-channel chunk: c0 = c8*32
  const int tap = sl >> 3;        // 0..8
  const int b0  = xcd << 2;
  const int t   = threadIdx.x;
  __shared__ bf16_t tile[4][32 * 260];

  float a[4][4];
#pragma unroll
  for (int i = 0; i < 4; ++i)
#pragma unroll
    for (int k = 0; k < 4; ++k) a[i][k] = attn[(b0 + i) * 4 + k];

  const float* k0 = kers + ((size_t)(0 * 9 + tap)) * 65536 + (size_t)(c8 * 32) * 256;
  const float* k1 = kers + ((size_t)(1 * 9 + tap)) * 65536 + (size_t)(c8 * 32) * 256;
  const float* k2 = kers + ((size_t)(2 * 9 + tap)) * 65536 + (size_t)(c8 * 32) * 256;
  const float* k3 = kers + ((size_t)(3 * 9 + tap)) * 65536 + (size_t)(c8 * 32) * 256;

  const int fq = t & 63;       // f group: f0 = fq*4
  const int cl = t >> 6;       // 0..3
  const int f0 = fq * 4;
#pragma unroll
  for (int pass = 0; pass < 8; ++pass) {
    const int c_local = pass * 4 + cl;           // 0..31
    const size_t o = (size_t)c_local * 256 + f0;
    floatx4 v0 = *(const floatx4*)(k0 + o);
    floatx4 v1 = *(const floatx4*)(k1 + o);
    floatx4 v2 = *(const floatx4*)(k2 + o);
    floatx4 v3 = *(const floatx4*)(k3 + o);
#pragma unroll
    for (int i = 0; i < 4; ++i) {
      bf16x4 r;
#pragma unroll
      for (int j = 0; j < 4; ++j)
        r[j] = (bf16_t)(a[i][0] * v0[j] + a[i][1] * v1[j] + a[i][2] * v2[j] + a[i][3] * v3[j]);
      *(bf16x4*)&tile[i][c_local * 260 + f0] = r;   // 8B write, 8-aligned
    }
  }
  __syncthreads();

#pragma unroll
  for (int i = 0; i < 4; ++i) {
    bf16_t* wt = wagg + ((size_t)((b0 + i) * 9 + tap)) * 65536 + c8 * 32;
#pragma unroll
    for (int pass = 0; pass < 4; ++pass) {
      const int gi = pass * 256 + t;               // 0..1023
      const int f  = gi >> 2;                      // 0..255
      const int cg = gi & 3;                       // 0..3  (8-c granule within chunk)
      bf16x8 v;
#pragma unroll
      for (int jj = 0; jj < 8; ++jj) v[jj] = tile[i][(cg * 8 + jj) * 260 + f];
      *(bf16x8*)(wt + (size_t)f * 256 + cg * 8) = v;  // 16B store, 16-aligned
    }
  }
}

// ---------------- kernel 4: implicit-GEMM conv with per-sample weights ----------------
// v8: barrier-free main loop. B operands load global->VGPR per wave (wagg is
// L2-resident on the owning XCD; register deps need no barriers/asm waits, so
// waves drift across the 9 taps of a cq and the LDS/matrix pipes overlap via
// TLP instead of lockstep phases). A stays in LDS (4-way shared patch),
// double-buffered per cq; only 4 barriers total (cq transitions, patch
// visibility/WAR). B double-buffered in registers (prefetch next tap).
#define PBUF_BYTES 40960   // 320 pos (10 rows x 32 cols) * 128B

__global__ __launch_bounds__(512, 2)
void conv_mfma(const bf16_t* __restrict__ xpad, const bf16_t* __restrict__ wagg,
               const float* __restrict__ biasagg, float* __restrict__ out) {
  __shared__ char lds[2 * PBUF_BYTES];  // 81920 B
  char* ldsP0 = lds;
  char* ldsP1 = lds + PBUF_BYTES;

  // XCD swizzle: 448 blocks, 448 % 8 == 0 -> bijective; XCD x owns b = 4x..4x+3
  const int lid  = blockIdx.y * 14 + blockIdx.x;
  const int nid  = (lid & 7) * 56 + (lid >> 3);
  const int b    = nid / 14;
  const int tile = nid - b * 14;
  const int h0 = (tile >> 1) * 8;
  const int w0 = (tile & 1) * 28;

  const int tid  = threadIdx.x;
  const int lane = tid & 63;
  const int wv   = tid >> 6;     // 0..7
  const int mg   = wv >> 2;      // m-group (0: rows 0..111, 1: rows 112..223)
  const int fs   = wv & 3;       // f-slice
  const int l15  = lane & 15;
  const int quad = lane >> 4;
  const int n0   = fs * 64;

  const char* xb = (const char*)xpad + (size_t)b * (HP * WP * 256 * 2);
  const char* wb = (const char*)wagg + (size_t)b * (9 * 256 * 256 * 2);

  // static per-lane offsets
  int offs[7];
#pragma unroll
  for (int mi = 0; mi < 7; ++mi) {
    int m = mg * 112 + mi * 16 + l15;
    int ty = m / 28;
    int tx = m - ty * 28;
    offs[mi] = ty * 32 + tx;   // patch position index (32-col stride)
  }
  // per-lane B base: row f = n0+l15 (+ni*16), ks0 granule = quad*16
  const char* bbase = wb + (size_t)(n0 + l15) * 512 + quad * 16;
  int sp_off[5];
#pragma unroll
  for (int ii = 0; ii < 5; ++ii) {
    int i40 = wv * 5 + ii;
    int p = i40 * 8 + (lane >> 3);       // 0..319
    int row = p >> 5, col = p & 31;
    int gsrc = (lane & 7) ^ (p & 7);
    sp_off[ii] = ((h0 + row) * WP + (w0 + col)) * 512 + gsrc * 16;
  }

  floatx4 acc[7][4];
#pragma unroll
  for (int mi = 0; mi < 7; ++mi)
#pragma unroll
    for (int ni = 0; ni < 4; ++ni) acc[mi][ni] = (floatx4){0.f, 0.f, 0.f, 0.f};

  auto stage_patch = [&](int cq, char* pdst) {
#pragma unroll
    for (int ii = 0; ii < 5; ++ii)
      async_copy16(xb + cq * 128 + sp_off[ii], pdst + (wv * 5 + ii) * 1024);
  };
  // load 8 B fragments (4 ks0 + 4 ks1) for (cq,tap) into dst regs
  auto load_B = [&](int cq, int tap, bf16x8* dst) {
    const char* base = bbase + (size_t)tap * 131072 + cq * 128;
#pragma unroll
    for (int ni = 0; ni < 4; ++ni) {
      dst[ni]     = *(const bf16x8*)(base + ni * 8192);
      dst[4 + ni] = *(const bf16x8*)(base + ni * 8192 + 64);
    }
  };

  // prologue: patch cq0; own-drain + barrier => visible to all waves
  stage_patch(0, ldsP0);
  asm volatile("s_waitcnt vmcnt(0)" ::: "memory");
  __builtin_amdgcn_s_barrier();
  __builtin_amdgcn_sched_barrier(0);

  bf16x8 Bcur[8], Bnext[8];
  load_B(0, 0, Bcur);

  bf16x8 aA[7], aB[7];

#pragma unroll 1
  for (int d = 0; d < 36; ++d) {
    const int cq  = d / 9;
    const int tap = d - cq * 9;
    char* pbc = (cq & 1) ? ldsP1 : ldsP0;
    char* pbn = (cq & 1) ? ldsP0 : ldsP1;
    const bool haveNext = (d < 35);

    // stage next cq's patch early in the cq (WAR on pbn closed by the barrier
    // we just crossed; visibility established at next cq-boundary barrier)
    if (tap == 0 && cq < 3) stage_patch(cq + 1, pbn);

    // prefetch next tap's B straight to registers (no cross-wave hazard;
    // compiler/hw handle the register dependency via vmcnt)
    if (haveNext) {
      const int nt = (tap == 8) ? 0 : tap + 1;
      const int nc = (tap == 8) ? cq + 1 : cq;
      load_B(nc, nt, Bnext);
    }

    // A fragments for this tap (patch stable within the cq)
    const int tapoff = (tap / 3) * 32 + (tap % 3);
    int aoff[7];
#pragma unroll
    for (int mi = 0; mi < 7; ++mi) {
      int p = offs[mi] + tapoff;
      aoff[mi] = (p << 7) + ((quad ^ (p & 7)) << 4);
      aA[mi] = *(const bf16x8*)(pbc + aoff[mi]);
    }

    __builtin_amdgcn_s_setprio(1);
#pragma unroll
    for (int mi = 0; mi < 7; ++mi) {
      acc[mi][0] = __builtin_amdgcn_mfma_f32_16x16x32_bf16(aA[mi], Bcur[0], acc[mi][0], 0, 0, 0);
      acc[mi][1] = __builtin_amdgcn_mfma_f32_16x16x32_bf16(aA[mi], Bcur[1], acc[mi][1], 0, 0, 0);
      acc[mi][2] = __builtin_amdgcn_mfma_f32_16x16x32_bf16(aA[mi], Bcur[2], acc[mi][2], 0, 0, 0);
      acc[mi][3] = __builtin_amdgcn_mfma_f32_16x16x32_bf16(aA[mi], Bcur[3], acc[mi][3], 0, 0, 0);
    }
    __builtin_amdgcn_s_setprio(0);

#pragma unroll
    for (int mi = 0; mi < 7; ++mi)
      aB[mi] = *(const bf16x8*)(pbc + (aoff[mi] ^ 64));

    __builtin_amdgcn_s_setprio(1);
#pragma unroll
    for (int mi = 0; mi < 7; ++mi) {
      acc[mi][0] = __builtin_amdgcn_mfma_f32_16x16x32_bf16(aB[mi], Bcur[4], acc[mi][0], 0, 0, 0);
      acc[mi][1] = __builtin_amdgcn_mfma_f32_16x16x32_bf16(aB[mi], Bcur[5], acc[mi][1], 0, 0, 0);
      acc[mi][2] = __builtin_amdgcn_mfma_f32_16x16x32_bf16(aB[mi], Bcur[6], acc[mi][2], 0, 0, 0);
      acc[mi][3] = __builtin_amdgcn_mfma_f32_16x16x32_bf16(aB[mi], Bcur[7], acc[mi][3], 0, 0, 0);
    }
    __builtin_amdgcn_s_setprio(0);

    // cq-boundary: drain own patch-stage (+ in-flight B regs), then barrier.
    // Only 3 of these in the whole loop.
    if (tap == 8 && cq < 3) {
      asm volatile("s_waitcnt vmcnt(0)" ::: "memory");
      __builtin_amdgcn_s_barrier();
      __builtin_amdgcn_sched_barrier(0);
    }

    if (haveNext) {
#pragma unroll
      for (int i = 0; i < 8; ++i) Bcur[i] = Bnext[i];
    }
  }

  // epilogue: D layout col=lane&15 (f), row=quad*4+reg (m)
  float bias[4];
#pragma unroll
  for (int ni = 0; ni < 4; ++ni) bias[ni] = biasagg[b * 256 + n0 + ni * 16 + l15];
  float* outb = out + (size_t)b * (56 * 56 * 256);
#pragma unroll
  for (int mi = 0; mi < 7; ++mi) {
#pragma unroll
    for (int rg = 0; rg < 4; ++rg) {
      int m = mg * 112 + mi * 16 + quad * 4 + rg;
      int ty = m / 28, tx = m - ty * 28;
      float* orow = outb + ((size_t)((h0 + ty) * 56) + (w0 + tx)) * 256 + n0 + l15;
#pragma unroll
      for (int ni = 0; ni < 4; ++ni) orow[ni * 16] = acc[mi][ni][rg] + bias[ni];
    }
  }
}

extern "C" void kernel_launch(void* const* d_in, const int* in_sizes, int n_in,
                              void* d_out, int out_size, void* d_ws, size_t ws_size,
                              hipStream_t stream) {
  const float* x      = (const float*)d_in[0];
  const float* kers   = (const float*)d_in[1];
  const float* biases = (const float*)d_in[2];
  const float* w1     = (const float*)d_in[3];
  const float* b1     = (const float*)d_in[4];
  const float* w2     = (const float*)d_in[5];
  const float* b2     = (const float*)d_in[6];
  float* outp = (float*)d_out;
  char* ws = (char*)d_ws;

  bf16_t* xpad   = (bf16_t*)(ws + XPAD_OFF);
  bf16_t* wagg   = (bf16_t*)(ws + WAGG_OFF);
  float* pooled  = (float*)(ws + POOLED_OFF);
  float* attn    = (float*)(ws + ATTN_OFF);
  float* biasagg = (float*)(ws + BIASAGG_OFF);

  hipMemsetAsync(pooled, 0, 32 * 256 * sizeof(float), stream);
  pad_pool<<<dim3(58, 32), 256, 0, stream>>>(x, xpad, pooled);
  router<<<1, 256, 0, stream>>>(pooled, w1, b1, w2, b2, biases, attn, biasagg);
  wagg_kernel<<<dim3(576), 256, 0, stream>>>(kers, attn, wagg);
  conv_mfma<<<dim3(14, 32), 512, 0, stream>>>(xpad, wagg, biasagg, outp);
}

// Round 7
// 371.642 us; speedup vs baseline: 1.0810x; 1.0810x over previous
//
#include <hip/hip_runtime.h>
#include <hip/hip_bf16.h>
#include <stdint.h>

typedef __bf16 bf16_t;
typedef __bf16 bf16x4 __attribute__((ext_vector_type(4)));
typedef __bf16 bf16x8 __attribute__((ext_vector_type(8)));
typedef float floatx4 __attribute__((ext_vector_type(4)));

#define B_ 32
#define HP 58
#define WP 66

// ws layout (bytes)
#define XPAD_OFF   0u
#define WAGG_OFF   62717952u     // 32*58*66*256*2
#define POOLED_OFF 100466688u    // + 32*9*256*256*2 (wagg2 same size, new layout)
#define ATTN_OFF   100499456u
#define BIASAGG_OFF 100499968u

__device__ __forceinline__ void async_copy16(const void* gsrc, void* ldst) {
  __builtin_amdgcn_global_load_lds(
      (const __attribute__((address_space(1))) unsigned int*)gsrc,
      (__attribute__((address_space(3))) unsigned int*)ldst, 16, 0, 0);
}

// ---------------- kernel 1: pad + convert + GAP partial sums ----------------
__global__ __launch_bounds__(256)
void pad_pool(const float* __restrict__ x, bf16_t* __restrict__ xpad,
              float* __restrict__ pooled) {
  const int hp = blockIdx.x;   // 0..57
  const int b  = blockIdx.y;
  const int t  = threadIdx.x;
  const int c4 = (t & 63) << 2;   // 0..252 (float4 channel group)
  const int wq = t >> 6;          // 0..3
  const int h  = hp - 1;
  const bool hvalid = (h >= 0) && (h < 56);
  bf16_t* dst = xpad + ((size_t)(b * 58 + hp)) * (66 * 256);
  const float* srcrow = x + ((size_t)(b * 56 + (hvalid ? h : 0))) * (56 * 256);
  floatx4 sum = {0.f, 0.f, 0.f, 0.f};
  for (int wp = wq; wp < 66; wp += 4) {
    const int w = wp - 1;
    floatx4 v = {0.f, 0.f, 0.f, 0.f};
    if (hvalid && (unsigned)w < 56u) {
      v = *(const floatx4*)(srcrow + w * 256 + c4);
      sum += v;
    }
    bf16x4 r;
#pragma unroll
    for (int j = 0; j < 4; ++j) r[j] = (bf16_t)v[j];
    *(bf16x4*)(dst + wp * 256 + c4) = r;
  }
  __shared__ floatx4 red[4][64];
  red[wq][t & 63] = sum;
  __syncthreads();
  if (hvalid && t < 64) {
    floatx4 s = red[0][t] + red[1][t] + red[2][t] + red[3][t];
#pragma unroll
    for (int j = 0; j < 4; ++j) atomicAdd(&pooled[b * 256 + t * 4 + j], s[j]);
  }
}

// ---------------- kernel 2: router MLP + softmax + bias agg ----------------
__global__ __launch_bounds__(256)
void router(const float* __restrict__ pooled, const float* __restrict__ w1,
            const float* __restrict__ b1, const float* __restrict__ w2,
            const float* __restrict__ b2, const float* __restrict__ biases,
            float* __restrict__ attn, float* __restrict__ biasagg) {
  __shared__ float ps[8192];
  __shared__ float w1s[16384];
  __shared__ float hs[2048];
  __shared__ float lg[128];
  __shared__ float at[128];
  const int t = threadIdx.x;
  for (int i = t; i < 8192; i += 256) ps[i] = pooled[i] * (1.0f / 3136.0f);
  for (int i = t; i < 4096; i += 256)
    *(floatx4*)&w1s[i * 4] = *(const floatx4*)&w1[i * 4];
  __syncthreads();
  for (int task = t; task < 2048; task += 256) {
    const int b = task >> 6, j = task & 63;
    const float* pb = ps + b * 256;
    float s0 = 0.f, s1 = 0.f, s2 = 0.f, s3 = 0.f;
#pragma unroll 4
    for (int c = 0; c < 256; c += 4) {
      s0 += pb[c]     * w1s[c * 64 + j];
      s1 += pb[c + 1] * w1s[(c + 1) * 64 + j];
      s2 += pb[c + 2] * w1s[(c + 2) * 64 + j];
      s3 += pb[c + 3] * w1s[(c + 3) * 64 + j];
    }
    hs[task] = fmaxf((s0 + s1) + (s2 + s3) + b1[j], 0.f);
  }
  __syncthreads();
  if (t < 128) {
    int b = t >> 2, k = t & 3;
    float s = b2[k];
    const float* hb = hs + b * 64;
#pragma unroll 4
    for (int j = 0; j < 64; ++j) s += hb[j] * w2[j * 4 + k];
    lg[t] = s * (1.0f / 30.0f);
  }
  __syncthreads();
  if (t < 32) {
    int b = t;
    float z0 = lg[b*4], z1 = lg[b*4+1], z2 = lg[b*4+2], z3 = lg[b*4+3];
    float m = fmaxf(fmaxf(z0, z1), fmaxf(z2, z3));
    float e0 = expf(z0-m), e1 = expf(z1-m), e2 = expf(z2-m), e3 = expf(z3-m);
    float inv = 1.0f / (e0 + e1 + e2 + e3);
    at[b*4] = e0*inv; at[b*4+1] = e1*inv; at[b*4+2] = e2*inv; at[b*4+3] = e3*inv;
    attn[b*4] = at[b*4]; attn[b*4+1] = at[b*4+1];
    attn[b*4+2] = at[b*4+2]; attn[b*4+3] = at[b*4+3];
  }
  __syncthreads();
  for (int i = t; i < 8192; i += 256) {
    int b = i >> 8, f = i & 255;
    biasagg[i] = at[b*4]*biases[f] + at[b*4+1]*biases[256+f]
               + at[b*4+2]*biases[512+f] + at[b*4+3]*biases[768+f];
  }
}

// ---------------- kernel 3: weight agg + FRAGMENT-MAJOR layout ----------------
// v9: wagg2[b][tap][cq][fs][ks*4+ni][lane][8 bf16] — exactly the bytes each conv
// wave's B fragment needs, in lane order, so conv's load_B is 8 contiguous 1KB
// wave-reads. frag(ks,ni)[lane=q*16+l15][j] = W[tap][cq*64+ks*32+q*8+j][fs*64+ni*16+l15].
// Block per (xcd, 32-ch chunk c8=(cq,ks), tap), computing the 4 b's its XCD owns.
__global__ __launch_bounds__(256)
void wagg_kernel(const float* __restrict__ kers, const float* __restrict__ attn,
                 bf16_t* __restrict__ wagg) {
  const int lid = blockIdx.x;     // 0..575
  const int xcd = lid & 7;
  const int sl  = lid >> 3;       // 0..71
  const int c8  = sl & 7;         // 32-channel chunk: c0 = c8*32
  const int tap = sl >> 3;        // 0..8
  const int cq  = c8 >> 1;
  const int ks  = c8 & 1;
  const int b0  = xcd << 2;
  const int t   = threadIdx.x;
  __shared__ bf16_t tile[4][32 * 260];

  float a[4][4];
#pragma unroll
  for (int i = 0; i < 4; ++i)
#pragma unroll
    for (int k = 0; k < 4; ++k) a[i][k] = attn[(b0 + i) * 4 + k];

  const float* k0 = kers + ((size_t)(0 * 9 + tap)) * 65536 + (size_t)(c8 * 32) * 256;
  const float* k1 = kers + ((size_t)(1 * 9 + tap)) * 65536 + (size_t)(c8 * 32) * 256;
  const float* k2 = kers + ((size_t)(2 * 9 + tap)) * 65536 + (size_t)(c8 * 32) * 256;
  const float* k3 = kers + ((size_t)(3 * 9 + tap)) * 65536 + (size_t)(c8 * 32) * 256;

  const int fq = t & 63;       // f group: f0 = fq*4
  const int cl = t >> 6;       // 0..3
  const int f0 = fq * 4;
#pragma unroll
  for (int pass = 0; pass < 8; ++pass) {
    const int c_local = pass * 4 + cl;           // 0..31
    const size_t o = (size_t)c_local * 256 + f0;
    floatx4 v0 = *(const floatx4*)(k0 + o);
    floatx4 v1 = *(const floatx4*)(k1 + o);
    floatx4 v2 = *(const floatx4*)(k2 + o);
    floatx4 v3 = *(const floatx4*)(k3 + o);
#pragma unroll
    for (int i = 0; i < 4; ++i) {
      bf16x4 r;
#pragma unroll
      for (int j = 0; j < 4; ++j)
        r[j] = (bf16_t)(a[i][0] * v0[j] + a[i][1] * v1[j] + a[i][2] * v2[j] + a[i][3] * v3[j]);
      *(bf16x4*)&tile[i][c_local * 260 + f0] = r;   // tile[c_local][f] = W[c][f]
    }
  }
  __syncthreads();

  // readout: granule (fs,ni,q,l15) -> 8 channels j. Fully coalesced 16B stores.
#pragma unroll
  for (int i = 0; i < 4; ++i) {
    char* wt = (char*)wagg + (size_t)(b0 + i) * 1179648 + (size_t)tap * 131072
             + cq * 32768 + ks * 4096;
#pragma unroll
    for (int pass = 0; pass < 4; ++pass) {
      const int gi  = pass * 256 + t;              // 0..1023
      const int l15g = gi & 15;
      const int q    = (gi >> 4) & 3;
      const int ni   = (gi >> 6) & 3;
      const int fs   = gi >> 8;
      const int f    = fs * 64 + ni * 16 + l15g;
      bf16x8 v;
#pragma unroll
      for (int j = 0; j < 8; ++j) v[j] = tile[i][(q * 8 + j) * 260 + f];
      *(bf16x8*)(wt + fs * 8192 + ni * 1024 + q * 256 + l15g * 16) = v;
    }
  }
}

// ---------------- kernel 4: implicit-GEMM conv with per-sample weights ----------------
// v9: barrier-free main loop (4 barriers total, at cq boundaries). B operands load
// global->VGPR per wave from the fragment-major wagg2 (8 contiguous 1KB wave-reads
// per tap — v8's 16-line scatter was the regression). A in LDS (shared patch,
// double-buffered per cq). 2x-unrolled ping-pong B register sets (static indexing).
// Waves drift across the 9 taps of a cq -> LDS/matrix pipes overlap via TLP.
#define PBUF_BYTES 40960   // 320 pos (10 rows x 32 cols) * 128B

__global__ __launch_bounds__(512, 2)
void conv_mfma(const bf16_t* __restrict__ xpad, const bf16_t* __restrict__ wagg,
               const float* __restrict__ biasagg, float* __restrict__ out) {
  __shared__ char lds[2 * PBUF_BYTES];  // 81920 B
  char* ldsP0 = lds;
  char* ldsP1 = lds + PBUF_BYTES;

  // XCD swizzle: 448 blocks, 448 % 8 == 0 -> bijective; XCD x owns b = 4x..4x+3
  const int lid  = blockIdx.y * 14 + blockIdx.x;
  const int nid  = (lid & 7) * 56 + (lid >> 3);
  const int b    = nid / 14;
  const int tile = nid - b * 14;
  const int h0 = (tile >> 1) * 8;
  const int w0 = (tile & 1) * 28;

  const int tid  = threadIdx.x;
  const int lane = tid & 63;
  const int wv   = tid >> 6;     // 0..7
  const int mg   = wv >> 2;      // m-group (0: rows 0..111, 1: rows 112..223)
  const int fs   = wv & 3;       // f-slice
  const int l15  = lane & 15;
  const int quad = lane >> 4;
  const int n0   = fs * 64;

  const char* xb = (const char*)xpad + (size_t)b * (HP * WP * 256 * 2);
  const char* wb = (const char*)wagg + (size_t)b * 1179648 + fs * 8192 + (size_t)lane * 16;

  // static per-lane offsets
  int offs[7];
#pragma unroll
  for (int mi = 0; mi < 7; ++mi) {
    int m = mg * 112 + mi * 16 + l15;
    int ty = m / 28;
    int tx = m - ty * 28;
    offs[mi] = ty * 32 + tx;   // patch position index (32-col stride)
  }
  int sp_off[5];
#pragma unroll
  for (int ii = 0; ii < 5; ++ii) {
    int i40 = wv * 5 + ii;
    int p = i40 * 8 + (lane >> 3);       // 0..319
    int row = p >> 5, col = p & 31;
    int gsrc = (lane & 7) ^ (p & 7);
    sp_off[ii] = ((h0 + row) * WP + (w0 + col)) * 512 + gsrc * 16;
  }

  floatx4 acc[7][4];
#pragma unroll
  for (int mi = 0; mi < 7; ++mi)
#pragma unroll
    for (int ni = 0; ni < 4; ++ni) acc[mi][ni] = (floatx4){0.f, 0.f, 0.f, 0.f};

  auto stage_patch = [&](int cq, char* pdst) {
#pragma unroll
    for (int ii = 0; ii < 5; ++ii)
      async_copy16(xb + cq * 128 + sp_off[ii], pdst + (wv * 5 + ii) * 1024);
  };
  // 8 contiguous 1KB wave-reads: frag idx = ks*4+ni
  auto load_B = [&](int cq, int tap, bf16x8 (&dst)[8]) {
    const char* base = wb + (size_t)tap * 131072 + cq * 32768;
#pragma unroll
    for (int idx = 0; idx < 8; ++idx)
      dst[idx] = *(const bf16x8*)(base + idx * 1024);
  };

  // one tap-period: MFMA from `cur`, prefetch next tap's B into `nxt`
  auto step = [&](int d, bf16x8 (&cur)[8], bf16x8 (&nxt)[8]) {
    const int cq  = d / 9;
    const int tap = d - cq * 9;
    char* pbc = (cq & 1) ? ldsP1 : ldsP0;
    char* pbn = (cq & 1) ? ldsP0 : ldsP1;

    if (tap == 0 && cq < 3) stage_patch(cq + 1, pbn);

    if (d < 35) {
      const int nt = (tap == 8) ? 0 : tap + 1;
      const int nc = (tap == 8) ? cq + 1 : cq;
      load_B(nc, nt, nxt);
    }

    const int tapoff = (tap / 3) * 32 + (tap % 3);
    int aoff[7];
    bf16x8 aA[7], aB[7];
#pragma unroll
    for (int mi = 0; mi < 7; ++mi) {
      int p = offs[mi] + tapoff;
      aoff[mi] = (p << 7) + ((quad ^ (p & 7)) << 4);
      aA[mi] = *(const bf16x8*)(pbc + aoff[mi]);
    }

    __builtin_amdgcn_s_setprio(1);
#pragma unroll
    for (int mi = 0; mi < 7; ++mi) {
      acc[mi][0] = __builtin_amdgcn_mfma_f32_16x16x32_bf16(aA[mi], cur[0], acc[mi][0], 0, 0, 0);
      acc[mi][1] = __builtin_amdgcn_mfma_f32_16x16x32_bf16(aA[mi], cur[1], acc[mi][1], 0, 0, 0);
      acc[mi][2] = __builtin_amdgcn_mfma_f32_16x16x32_bf16(aA[mi], cur[2], acc[mi][2], 0, 0, 0);
      acc[mi][3] = __builtin_amdgcn_mfma_f32_16x16x32_bf16(aA[mi], cur[3], acc[mi][3], 0, 0, 0);
    }
    __builtin_amdgcn_s_setprio(0);

#pragma unroll
    for (int mi = 0; mi < 7; ++mi)
      aB[mi] = *(const bf16x8*)(pbc + (aoff[mi] ^ 64));

    __builtin_amdgcn_s_setprio(1);
#pragma unroll
    for (int mi = 0; mi < 7; ++mi) {
      acc[mi][0] = __builtin_amdgcn_mfma_f32_16x16x32_bf16(aB[mi], cur[4], acc[mi][0], 0, 0, 0);
      acc[mi][1] = __builtin_amdgcn_mfma_f32_16x16x32_bf16(aB[mi], cur[5], acc[mi][1], 0, 0, 0);
      acc[mi][2] = __builtin_amdgcn_mfma_f32_16x16x32_bf16(aB[mi], cur[6], acc[mi][2], 0, 0, 0);
      acc[mi][3] = __builtin_amdgcn_mfma_f32_16x16x32_bf16(aB[mi], cur[7], acc[mi][3], 0, 0, 0);
    }
    __builtin_amdgcn_s_setprio(0);

    // cq-boundary: drain own patch-stage, then barrier (3 total in the loop)
    if (tap == 8 && cq < 3) {
      asm volatile("s_waitcnt vmcnt(0)" ::: "memory");
      __builtin_amdgcn_s_barrier();
      __builtin_amdgcn_sched_barrier(0);
    }
  };

  // prologue: patch cq0; own-drain + barrier => visible to all waves
  stage_patch(0, ldsP0);
  asm volatile("s_waitcnt vmcnt(0)" ::: "memory");
  __builtin_amdgcn_s_barrier();
  __builtin_amdgcn_sched_barrier(0);

  bf16x8 BA[8], BB[8];
  load_B(0, 0, BA);

#pragma unroll 1
  for (int dp = 0; dp < 18; ++dp) {
    step(2 * dp,     BA, BB);
    step(2 * dp + 1, BB, BA);
  }

  // epilogue: D layout col=lane&15 (f), row=quad*4+reg (m)
  float bias[4];
#pragma unroll
  for (int ni = 0; ni < 4; ++ni) bias[ni] = biasagg[b * 256 + n0 + ni * 16 + l15];
  float* outb = out + (size_t)b * (56 * 56 * 256);
#pragma unroll
  for (int mi = 0; mi < 7; ++mi) {
#pragma unroll
    for (int rg = 0; rg < 4; ++rg) {
      int m = mg * 112 + mi * 16 + quad * 4 + rg;
      int ty = m / 28, tx = m - ty * 28;
      float* orow = outb + ((size_t)((h0 + ty) * 56) + (w0 + tx)) * 256 + n0 + l15;
#pragma unroll
      for (int ni = 0; ni < 4; ++ni) orow[ni * 16] = acc[mi][ni][rg] + bias[ni];
    }
  }
}

extern "C" void kernel_launch(void* const* d_in, const int* in_sizes, int n_in,
                              void* d_out, int out_size, void* d_ws, size_t ws_size,
                              hipStream_t stream) {
  const float* x      = (const float*)d_in[0];
  const float* kers   = (const float*)d_in[1];
  const float* biases = (const float*)d_in[2];
  const float* w1     = (const float*)d_in[3];
  const float* b1     = (const float*)d_in[4];
  const float* w2     = (const float*)d_in[5];
  const float* b2     = (const float*)d_in[6];
  float* outp = (float*)d_out;
  char* ws = (char*)d_ws;

  bf16_t* xpad   = (bf16_t*)(ws + XPAD_OFF);
  bf16_t* wagg   = (bf16_t*)(ws + WAGG_OFF);
  float* pooled  = (float*)(ws + POOLED_OFF);
  float* attn    = (float*)(ws + ATTN_OFF);
  float* biasagg = (float*)(ws + BIASAGG_OFF);

  hipMemsetAsync(pooled, 0, 32 * 256 * sizeof(float), stream);
  pad_pool<<<dim3(58, 32), 256, 0, stream>>>(x, xpad, pooled);
  router<<<1, 256, 0, stream>>>(pooled, w1, b1, w2, b2, biases, attn, biasagg);
  wagg_kernel<<<dim3(576), 256, 0, stream>>>(kers, attn, wagg);
  conv_mfma<<<dim3(14, 32), 512, 0, stream>>>(xpad, wagg, biasagg, outp);
}